// Round 2
// baseline (380.387 us; speedup 1.0000x reference)
//
#include <hip/hip_runtime.h>
#include <hip/hip_bf16.h>

using f32x4  = __attribute__((ext_vector_type(4))) float;
using u32x4  = __attribute__((ext_vector_type(4))) unsigned int;
using bf16x8 = __attribute__((ext_vector_type(8))) short;

__device__ __forceinline__ ushort f2bf(float x) {
    union { __hip_bfloat16 h; ushort u; } cv;
    cv.h = __float2bfloat16(x);
    return cv.u;
}
__device__ __forceinline__ unsigned pk2(float lo, float hi) {
    return (unsigned)f2bf(lo) | ((unsigned)f2bf(hi) << 16);
}
__device__ __forceinline__ float sigmoidf_(float x) { return 1.f / (1.f + expf(-x)); }

// ---------------------------------------------------------------------------
// GEMM: C[M,N] = A([M,K], f32 or bf16) * B(bf16,[K,N]) (+bias, relu, bf16/f32)
// BM=128, BN=64, BK=32. 256 threads = 4 waves (2x2), wave tile 64x32.
// SPLIT: blockIdx.z selects K-chunk, writes f32 partial at Cf + z*M*N.
// ---------------------------------------------------------------------------
template<bool A_BF16, bool SPLIT, bool RELU, bool BF16_OUT, bool HAS_BIAS>
__global__ __launch_bounds__(256)
void gemm_kernel(const void* __restrict__ Avoid, const ushort* __restrict__ B,
                 const float* __restrict__ bias, float* __restrict__ Cf,
                 ushort* __restrict__ Cb, int M, int N, int K, int ldc, int kPerChunk)
{
    __shared__ ushort As[128 * 40];
    __shared__ ushort Bs[64 * 40];
    const int tid  = threadIdx.x;
    const int lane = tid & 63;
    const int wid  = tid >> 6;
    const int wr   = wid >> 1, wc = wid & 1;
    const int g    = lane >> 4, lr = lane & 15;
    const long m0  = (long)blockIdx.x * 128;
    const int  n0  = blockIdx.y * 64;

    int kbeg = 0, kend = K;
    if (SPLIT) { kbeg = blockIdx.z * kPerChunk; kend = kbeg + kPerChunk; if (kend > K) kend = K; }

    const int bkr = tid & 31;   // B k-row within tile
    const int bcb = tid >> 5;   // B col-octet

    const float*  Af = (const float*)Avoid;
    const ushort* Ab = (const ushort*)Avoid;

    f32x4 pa[4];
    u32x4 pab[2];
    u32x4 pb;

    auto loadT = [&](int k0) {
        if (A_BF16) {
#pragma unroll
            for (int i = 0; i < 2; i++) {
                int s = tid + 256 * i; int row = s >> 2, c8 = s & 3;
                pab[i] = *(const u32x4*)(Ab + (m0 + row) * (long)K + k0 + c8 * 8);
            }
        } else {
#pragma unroll
            for (int i = 0; i < 4; i++) {
                int s = tid + 256 * i; int row = s >> 3, c4 = s & 7;
                pa[i] = *(const f32x4*)(Af + (m0 + row) * (long)K + k0 + c4 * 4);
            }
        }
        pb = *(const u32x4*)(B + (long)(k0 + bkr) * N + n0 + bcb * 8);
    };
    auto storeT = [&]() {
        if (A_BF16) {
#pragma unroll
            for (int i = 0; i < 2; i++) {
                int s = tid + 256 * i; int row = s >> 2, c8 = s & 3;
                *(u32x4*)(&As[row * 40 + c8 * 8]) = pab[i];
            }
        } else {
#pragma unroll
            for (int i = 0; i < 4; i++) {
                int s = tid + 256 * i; int row = s >> 3, c4 = s & 7;
                ushort4 w;
                w.x = f2bf(pa[i].x); w.y = f2bf(pa[i].y);
                w.z = f2bf(pa[i].z); w.w = f2bf(pa[i].w);
                *(ushort4*)(&As[row * 40 + c4 * 4]) = w;
            }
        }
        const ushort* p8 = (const ushort*)&pb;
#pragma unroll
        for (int j = 0; j < 8; j++) Bs[(bcb * 8 + j) * 40 + bkr] = p8[j];
    };

    f32x4 acc[4][2] = {};

    const int nk = (kend - kbeg) >> 5;
    loadT(kbeg);
    for (int t = 0; t < nk; ++t) {
        storeT();
        __syncthreads();
        if (t + 1 < nk) loadT(kbeg + ((t + 1) << 5));
        bf16x8 af[4], bfr[2];
#pragma unroll
        for (int fm = 0; fm < 4; fm++)
            af[fm] = *(const bf16x8*)(&As[(wr * 64 + fm * 16 + lr) * 40 + g * 8]);
#pragma unroll
        for (int fn = 0; fn < 2; fn++)
            bfr[fn] = *(const bf16x8*)(&Bs[(wc * 32 + fn * 16 + lr) * 40 + g * 8]);
#pragma unroll
        for (int fm = 0; fm < 4; fm++)
#pragma unroll
            for (int fn = 0; fn < 2; fn++)
                acc[fm][fn] = __builtin_amdgcn_mfma_f32_16x16x32_bf16(af[fm], bfr[fn], acc[fm][fn], 0, 0, 0);
        __syncthreads();
    }

    if (SPLIT) {
        float* P = Cf + (long)blockIdx.z * M * N;
#pragma unroll
        for (int fm = 0; fm < 4; fm++)
#pragma unroll
            for (int fn = 0; fn < 2; fn++)
#pragma unroll
                for (int rr = 0; rr < 4; rr++) {
                    long row = m0 + wr * 64 + fm * 16 + g * 4 + rr;
                    int  col = n0 + wc * 32 + fn * 16 + lr;
                    P[row * N + col] = acc[fm][fn][rr];
                }
    } else {
#pragma unroll
        for (int fm = 0; fm < 4; fm++)
#pragma unroll
            for (int fn = 0; fn < 2; fn++)
#pragma unroll
                for (int rr = 0; rr < 4; rr++) {
                    long row = m0 + wr * 64 + fm * 16 + g * 4 + rr;
                    int  col = n0 + wc * 32 + fn * 16 + lr;
                    float v = acc[fm][fn][rr];
                    if (HAS_BIAS) v += bias[col];
                    if (RELU) v = fmaxf(v, 0.f);
                    if (BF16_OUT) Cb[row * ldc + col] = f2bf(v);
                    else          Cf[row * ldc + col] = v;
                }
    }
}

// sum nz split-K partials -> bf16
__global__ __launch_bounds__(256) void reduce_add_bf16(const float* __restrict__ P,
                                                       ushort* __restrict__ C, int MN, int nz)
{
    int i = blockIdx.x * 256 + threadIdx.x;
    int n4 = MN >> 2;
    if (i >= n4) return;
    f32x4 a = ((const f32x4*)P)[i];
    for (int z = 1; z < nz; z++) a += ((const f32x4*)(P + (long)z * MN))[i];
    ushort4 o; o.x = f2bf(a.x); o.y = f2bf(a.y); o.z = f2bf(a.z); o.w = f2bf(a.w);
    ((ushort4*)C)[i] = o;
}

// prep: A->bf16, X_n->bf16, 3 weight transposes, zero stats. One launch.
__global__ __launch_bounds__(256) void prep_k(const float* __restrict__ A, ushort* __restrict__ Abf,
                                              const float* __restrict__ Xn, ushort* __restrict__ Xnb,
                                              const float* __restrict__ W1, ushort* __restrict__ W1t,
                                              const float* __restrict__ W2, ushort* __restrict__ W2t,
                                              const float* __restrict__ Wh, ushort* __restrict__ Wht,
                                              float* __restrict__ stats)
{
    int b = blockIdx.x, t = threadIdx.x;
    if (b < 8192) {                       // A: 16.78M elems, 8/thread
        long j = (long)b * 256 + t;
        f32x4 v0 = ((const f32x4*)A)[2 * j];
        f32x4 v1 = ((const f32x4*)A)[2 * j + 1];
        u32x4 w;
        w.x = pk2(v0.x, v0.y); w.y = pk2(v0.z, v0.w);
        w.z = pk2(v1.x, v1.y); w.w = pk2(v1.z, v1.w);
        ((u32x4*)Abf)[j] = w;
    } else if (b < 8448) {                // X_n: 524288 elems, 8/thread
        long j = (long)(b - 8192) * 256 + t;
        f32x4 v0 = ((const f32x4*)Xn)[2 * j];
        f32x4 v1 = ((const f32x4*)Xn)[2 * j + 1];
        u32x4 w;
        w.x = pk2(v0.x, v0.y); w.y = pk2(v0.z, v0.w);
        w.z = pk2(v1.x, v1.y); w.w = pk2(v1.z, v1.w);
        ((u32x4*)Xnb)[j] = w;
    } else if (b < 8576) {                // W1 [256,128] -> T [128,256]
        int j = (b - 8448) * 256 + t;
        int i = j >> 8, o = j & 255;
        W1t[j] = f2bf(W1[o * 128 + i]);
    } else if (b < 8832) {                // W2 [256,256] -> T [256,256]
        int j = (b - 8576) * 256 + t;
        int i = j >> 8, o = j & 255;
        W2t[j] = f2bf(W2[o * 256 + i]);
    } else if (b < 8848) {                // Wh [64,64] -> T [64,64]
        int j = (b - 8832) * 256 + t;
        int i = j >> 6, o = j & 63;
        Wht[j] = f2bf(Wh[o * 64 + i]);
    } else {
        if (t < 192) stats[t] = 0.f;
    }
}

// fused: Zc1 = sum of 4 partials; column sum/sumsq stats. grid 64 x 256
__global__ __launch_bounds__(256) void bnred_k(const float* __restrict__ P,
                                               float* __restrict__ Zc,
                                               float* __restrict__ gsum, float* __restrict__ gsq)
{
    const int MN = 8192 * 64;
    int b = blockIdx.x, t = threadIdx.x;
    int c = t & 63, rg = t >> 6;
    float sx = 0.f, sq = 0.f;
    int base = b * 128 + rg;
#pragma unroll 8
    for (int i = 0; i < 32; i++) {
        long idx = (long)(base + 4 * i) * 64 + c;
        float x = P[idx] + P[idx + MN] + P[idx + 2 * MN] + P[idx + 3 * MN];
        Zc[idx] = x;
        sx += x; sq += x * x;
    }
    __shared__ float ls[256], lq[256];
    ls[t] = sx; lq[t] = sq;
    __syncthreads();
    if (t < 64) {
        float a = ls[t] + ls[t + 64] + ls[t + 128] + ls[t + 192];
        float q = lq[t] + lq[t + 64] + lq[t + 128] + lq[t + 192];
        atomicAdd(&gsum[t], a);
        atomicAdd(&gsq[t], q);
    }
}

// Z1[row] = max_c relu(bn(Zc1[row,c])); wave per row, grid 2048 x 256
__global__ __launch_bounds__(256) void z1_k(const float* __restrict__ Zc,
                                            const float* __restrict__ gsum, const float* __restrict__ gsq,
                                            const float* __restrict__ g, const float* __restrict__ b,
                                            float* __restrict__ Z1)
{
    int w = threadIdx.x >> 6, lane = threadIdx.x & 63;
    int row = blockIdx.x * 4 + w;
    const float inv = 1.f / 8192.f;
    float m = gsum[lane] * inv;
    float v = gsq[lane] * inv - m * m;
    float x = Zc[row * 64 + lane];
    float y = fmaxf(g[lane] * (x - m) * rsqrtf(v + 1e-5f) + b[lane], 0.f);
#pragma unroll
    for (int o = 32; o > 0; o >>= 1) y = fmaxf(y, __shfl_xor(y, o));
    if (lane == 0) Z1[row] = y;
}

// s[i]=L1[i,:].Z1 ; r[i]=rowsum(L1[i,:]); fused 5-moment stats. wave/row, grid 2048
__global__ __launch_bounds__(256) void pass2_k(const float* __restrict__ L1, const float* __restrict__ Z1,
                                               float* __restrict__ s, float* __restrict__ r,
                                               float* __restrict__ S5)
{
    int w = threadIdx.x >> 6, l = threadIdx.x & 63;
    int row = blockIdx.x * 4 + w;
    const f32x4* rp = (const f32x4*)(L1 + (long)row * 8192);
    const f32x4* z4 = (const f32x4*)Z1;
    float as = 0.f, ar = 0.f;
#pragma unroll
    for (int k = 0; k < 32; k++) {
        f32x4 v = rp[l + 64 * k];
        f32x4 z = z4[l + 64 * k];
        as += v.x * z.x + v.y * z.y + v.z * z.z + v.w * z.w;
        ar += v.x + v.y + v.z + v.w;
    }
#pragma unroll
    for (int o = 32; o > 0; o >>= 1) { as += __shfl_xor(as, o); ar += __shfl_xor(ar, o); }
    __shared__ float sw[4], rw[4];
    if (l == 0) { s[row] = as; r[row] = ar; sw[w] = as; rw[w] = ar; }
    __syncthreads();
    if (threadIdx.x == 0) {
        float Ss = 0, Sr = 0, Sss = 0, Srr = 0, Ssr = 0;
#pragma unroll
        for (int i = 0; i < 4; i++) {
            float sv = sw[i], rv = rw[i];
            Ss += sv; Sr += rv; Sss += sv * sv; Srr += rv * rv; Ssr += sv * rv;
        }
        atomicAdd(&S5[0], Ss); atomicAdd(&S5[1], Sr);
        atomicAdd(&S5[2], Sss); atomicAdd(&S5[3], Srr); atomicAdd(&S5[4], Ssr);
    }
}

// Z2 + edge_prob; wave per row; grid 2048 x 256
__global__ __launch_bounds__(256) void z2_edge_k(const float* __restrict__ s, const float* __restrict__ r,
                                                 const float* __restrict__ S,
                                                 const float* __restrict__ W2, const float* __restrict__ b2,
                                                 const float* __restrict__ g2, const float* __restrict__ bb2,
                                                 const float* __restrict__ eW, const float* __restrict__ eb,
                                                 const float* __restrict__ Z1,
                                                 float* __restrict__ Z2, float* __restrict__ edge_out)
{
    int w = threadIdx.x >> 6, lane = threadIdx.x & 63;
    int row = blockIdx.x * 4 + w;
    const float inv = 1.f / 8192.f;
    float ms = S[0] * inv, mr = S[1] * inv;
    float vs = S[2] * inv - ms * ms;
    float vr = S[3] * inv - mr * mr;
    float cv = S[4] * inv - ms * mr;
    float w2 = W2[lane], bz = b2[lane];
    float mc = w2 * ms + bz * mr;
    float vc = w2 * w2 * vs + 2.f * w2 * bz * cv + bz * bz * vr;
    float x  = w2 * s[row] + bz * r[row];
    float y  = fmaxf(g2[lane] * (x - mc) * rsqrtf(vc + 1e-5f) + bb2[lane], 0.f);
#pragma unroll
    for (int o = 32; o > 0; o >>= 1) y = fmaxf(y, __shfl_xor(y, o));
    if (lane == 0) {
        Z2[row] = y;
        float e = Z1[row] * eW[0] + y * eW[1] + eb[0];
        edge_out[row] = sigmoidf_(e);
    }
}

// H_e (B1@[Z1 Z2]) into hcat cols 256/257 + node head; wave/row, grid 1024
__global__ __launch_bounds__(256) void he_node_k(const float* __restrict__ B1, const float* __restrict__ Z1,
                                                 const float* __restrict__ Z2, float* __restrict__ hcat,
                                                 const float* __restrict__ nW, const float* __restrict__ nb,
                                                 float* __restrict__ node_out)
{
    int w = threadIdx.x >> 6, l = threadIdx.x & 63;
    int n = blockIdx.x * 4 + w;
    const f32x4* rp  = (const f32x4*)(B1 + (long)n * 8192);
    const f32x4* z1v = (const f32x4*)Z1;
    const f32x4* z2v = (const f32x4*)Z2;
    float a1 = 0.f, a2 = 0.f;
#pragma unroll
    for (int k = 0; k < 32; k++) {
        f32x4 v = rp[l + 64 * k];
        f32x4 p = z1v[l + 64 * k];
        f32x4 q = z2v[l + 64 * k];
        a1 += v.x * p.x + v.y * p.y + v.z * p.z + v.w * p.w;
        a2 += v.x * q.x + v.y * q.y + v.z * q.z + v.w * q.w;
    }
#pragma unroll
    for (int o = 32; o > 0; o >>= 1) { a1 += __shfl_xor(a1, o); a2 += __shfl_xor(a2, o); }
    if (l == 0) {
        hcat[(long)n * 258 + 256] = a1;
        hcat[(long)n * 258 + 257] = a2;
    }
    const float* hr = hcat + (long)n * 258;
    float d = 0.f;
#pragma unroll
    for (int i = 0; i < 4; i++) d += hr[l + 64 * i] * nW[l + 64 * i];
#pragma unroll
    for (int o = 32; o > 0; o >>= 1) d += __shfl_xor(d, o);
    if (l == 0)
        node_out[n] = sigmoidf_(d + a1 * nW[256] + a2 * nW[257] + nb[0]);
}

// hyperedge gather-mean-dot-sigmoid; wave per hyperedge; grid 256 x 256
__global__ __launch_bounds__(256) void hyper_k(const void* __restrict__ he_idx,
                                               const float* __restrict__ hcat,
                                               const float* __restrict__ hW, const float* __restrict__ hb,
                                               float* __restrict__ out)
{
    int w = threadIdx.x >> 6, lane = threadIdx.x & 63;
    int h = blockIdx.x * 4 + w;
    const unsigned int* u = (const unsigned int*)he_idx;
    unsigned int odd = u[2 * lane + 1];
    bool is64 = __all(odd == 0u);
    float acc = 0.f;
    for (int k = 0; k < 8; k++) {
        int idx;
        if (is64) idx = (int)((const long long*)he_idx)[h * 8 + k];
        else      idx = ((const int*)he_idx)[h * 8 + k];
        const float* hr = hcat + (long)idx * 258;
        for (int d = lane; d < 258; d += 64) acc += hr[d] * hW[d];
    }
    acc *= 0.125f;
#pragma unroll
    for (int o = 32; o > 0; o >>= 1) acc += __shfl_xor(acc, o);
    if (lane == 0) out[h] = sigmoidf_(acc + hb[0]);
}

// ---------------------------------------------------------------------------
extern "C" void kernel_launch(void* const* d_in, const int* in_sizes, int n_in,
                              void* d_out, int out_size, void* d_ws, size_t ws_size,
                              hipStream_t stream)
{
    const float* X_n  = (const float*)d_in[0];
    const float* X_e  = (const float*)d_in[1];
    const float* A_t  = (const float*)d_in[2];
    const float* L1   = (const float*)d_in[3];
    const float* B1   = (const float*)d_in[4];
    const float* gW1  = (const float*)d_in[5];
    const float* gb1  = (const float*)d_in[6];
    const float* gW2  = (const float*)d_in[7];
    const float* gb2  = (const float*)d_in[8];
    const float* hW1  = (const float*)d_in[9];
    const float* hb1  = (const float*)d_in[10];
    const float* bn1g = (const float*)d_in[11];
    const float* bn1b = (const float*)d_in[12];
    const float* hW2  = (const float*)d_in[13];
    const float* hb2  = (const float*)d_in[14];
    const float* bn2g = (const float*)d_in[15];
    const float* bn2b = (const float*)d_in[16];
    const float* nW   = (const float*)d_in[17];
    const float* nb   = (const float*)d_in[18];
    const float* eW   = (const float*)d_in[19];
    const float* ebb  = (const float*)d_in[20];
    const float* yW   = (const float*)d_in[21];
    const float* yb   = (const float*)d_in[22];
    const void*  he   = d_in[23];

    float* out       = (float*)d_out;
    float* out_node  = out;              // 4096
    float* out_edge  = out + 4096;       // 8192
    float* out_hyper = out + 12288;      // 1024
    float* hcat      = out + 13312;      // 4096 x 258

    size_t off = 0;
    auto alloc = [&](size_t bytes) {
        void* p = (char*)d_ws + off;
        off = (off + bytes + 255) & ~(size_t)255;
        return p;
    };
    ushort* Abf   = (ushort*)alloc((size_t)4096 * 4096 * 2);  // 33.5 MB
    ushort* Xn_bf = (ushort*)alloc(4096 * 128 * 2);
    ushort* W1t   = (ushort*)alloc(128 * 256 * 2);
    ushort* W2t   = (ushort*)alloc(256 * 256 * 2);
    ushort* W1ht  = (ushort*)alloc(64 * 64 * 2);
    ushort* C1b   = (ushort*)alloc(4096 * 128 * 2);
    ushort* H_bf  = (ushort*)alloc(4096 * 256 * 2);
    ushort* C2b   = (ushort*)alloc(4096 * 256 * 2);
    ushort* Zt1   = (ushort*)alloc(8192 * 64 * 2);
    float*  Zc1   = (float*)alloc(8192 * 64 * 4);
    float*  stats = (float*)alloc(256 * 4);   // gsum[64], gsq[64], S5[5]
    float*  gsum  = stats;
    float*  gsq   = stats + 64;
    float*  S5    = stats + 128;
    float*  Z1    = (float*)alloc(8192 * 4);
    float*  Z2    = (float*)alloc(8192 * 4);
    float*  sbuf  = (float*)alloc(8192 * 4);
    float*  rbuf  = (float*)alloc(8192 * 4);
    float*  P     = (float*)alloc((size_t)2097152 * 4);  // split-K partials (8 MB)

    // prep: converts + transposes + stat zero (1 launch)
    prep_k<<<8849, 256, 0, stream>>>(A_t, Abf, X_n, Xn_bf, gW1, W1t, gW2, W2t, hW1, W1ht, stats);

    // GNN
    gemm_kernel<true, true, false, false, false><<<dim3(32, 2, 4), 256, 0, stream>>>(
        Abf, Xn_bf, nullptr, P, nullptr, 4096, 128, 4096, 128, 1024);
    reduce_add_bf16<<<512, 256, 0, stream>>>(P, C1b, 4096 * 128, 4);
    gemm_kernel<true, false, true, true, true><<<dim3(32, 4, 1), 256, 0, stream>>>(
        C1b, W1t, gb1, nullptr, H_bf, 4096, 256, 128, 256, 0);
    gemm_kernel<true, true, false, false, false><<<dim3(32, 4, 2), 256, 0, stream>>>(
        Abf, H_bf, nullptr, P, nullptr, 4096, 256, 4096, 256, 2048);
    reduce_add_bf16<<<1024, 256, 0, stream>>>(P, C2b, 4096 * 256, 2);
    gemm_kernel<true, false, true, false, true><<<dim3(32, 4, 1), 256, 0, stream>>>(
        C2b, W2t, gb2, hcat, nullptr, 4096, 256, 256, 258, 0);

    // HoSC layer 1
    gemm_kernel<false, false, false, true, true><<<dim3(64, 1, 1), 256, 0, stream>>>(
        X_e, W1ht, hb1, nullptr, Zt1, 8192, 64, 64, 64, 0);
    gemm_kernel<false, true, false, false, false><<<dim3(64, 1, 4), 256, 0, stream>>>(
        L1, Zt1, nullptr, P, nullptr, 8192, 64, 8192, 64, 2048);
    bnred_k<<<64, 256, 0, stream>>>(P, Zc1, gsum, gsq);
    z1_k<<<2048, 256, 0, stream>>>(Zc1, gsum, gsq, bn1g, bn1b, Z1);

    // HoSC layer 2 (rank-1 collapse) + fused stats
    pass2_k<<<2048, 256, 0, stream>>>(L1, Z1, sbuf, rbuf, S5);
    z2_edge_k<<<2048, 256, 0, stream>>>(sbuf, rbuf, S5, hW2, hb2, bn2g, bn2b,
                                        eW, ebb, Z1, Z2, out_edge);

    // fuse + heads
    he_node_k<<<1024, 256, 0, stream>>>(B1, Z1, Z2, hcat, nW, nb, out_node);
    hyper_k<<<256, 256, 0, stream>>>(he, hcat, yW, yb, out_hyper);
}

// Round 3
// 293.868 us; speedup vs baseline: 1.2944x; 1.2944x over previous
//
#include <hip/hip_runtime.h>
#include <hip/hip_bf16.h>

using f32x4  = __attribute__((ext_vector_type(4))) float;
using u32x4  = __attribute__((ext_vector_type(4))) unsigned int;
using bf16x8 = __attribute__((ext_vector_type(8))) short;

__device__ __forceinline__ ushort f2bf(float x) {
    union { __hip_bfloat16 h; ushort u; } cv;
    cv.h = __float2bfloat16(x);
    return cv.u;
}
__device__ __forceinline__ unsigned pk2(float lo, float hi) {
    return (unsigned)f2bf(lo) | ((unsigned)f2bf(hi) << 16);
}
__device__ __forceinline__ float sigmoidf_(float x) { return 1.f / (1.f + expf(-x)); }

// ---------------------------------------------------------------------------
// GEMM: C[M,N] = A([M,K], f32 or bf16) * B(bf16,[K,N]) (+bias, relu, bf16/f32)
// BM=128, BN=64, BK=32. 256 threads = 4 waves (2x2), wave tile 64x32.
// SPLIT: blockIdx.z selects K-chunk, writes f32 partial at Cf + z*M*N.
// ---------------------------------------------------------------------------
template<bool A_BF16, bool SPLIT, bool RELU, bool BF16_OUT, bool HAS_BIAS>
__global__ __launch_bounds__(256)
void gemm_kernel(const void* __restrict__ Avoid, const ushort* __restrict__ B,
                 const float* __restrict__ bias, float* __restrict__ Cf,
                 ushort* __restrict__ Cb, int M, int N, int K, int ldc, int kPerChunk)
{
    __shared__ ushort As[128 * 40];
    __shared__ ushort Bs[64 * 40];
    const int tid  = threadIdx.x;
    const int lane = tid & 63;
    const int wid  = tid >> 6;
    const int wr   = wid >> 1, wc = wid & 1;
    const int g    = lane >> 4, lr = lane & 15;
    const long m0  = (long)blockIdx.x * 128;
    const int  n0  = blockIdx.y * 64;

    int kbeg = 0, kend = K;
    if (SPLIT) { kbeg = blockIdx.z * kPerChunk; kend = kbeg + kPerChunk; if (kend > K) kend = K; }

    const int bkr = tid & 31;   // B k-row within tile
    const int bcb = tid >> 5;   // B col-octet

    const float*  Af = (const float*)Avoid;
    const ushort* Ab = (const ushort*)Avoid;

    f32x4 pa[4];
    u32x4 pab[2];
    u32x4 pb;

    auto loadT = [&](int k0) {
        if (A_BF16) {
#pragma unroll
            for (int i = 0; i < 2; i++) {
                int s = tid + 256 * i; int row = s >> 2, c8 = s & 3;
                pab[i] = *(const u32x4*)(Ab + (m0 + row) * (long)K + k0 + c8 * 8);
            }
        } else {
#pragma unroll
            for (int i = 0; i < 4; i++) {
                int s = tid + 256 * i; int row = s >> 3, c4 = s & 7;
                pa[i] = *(const f32x4*)(Af + (m0 + row) * (long)K + k0 + c4 * 4);
            }
        }
        pb = *(const u32x4*)(B + (long)(k0 + bkr) * N + n0 + bcb * 8);
    };
    auto storeT = [&]() {
        if (A_BF16) {
#pragma unroll
            for (int i = 0; i < 2; i++) {
                int s = tid + 256 * i; int row = s >> 2, c8 = s & 3;
                *(u32x4*)(&As[row * 40 + c8 * 8]) = pab[i];
            }
        } else {
#pragma unroll
            for (int i = 0; i < 4; i++) {
                int s = tid + 256 * i; int row = s >> 3, c4 = s & 7;
                ushort4 w;
                w.x = f2bf(pa[i].x); w.y = f2bf(pa[i].y);
                w.z = f2bf(pa[i].z); w.w = f2bf(pa[i].w);
                *(ushort4*)(&As[row * 40 + c4 * 4]) = w;
            }
        }
        const ushort* p8 = (const ushort*)&pb;
#pragma unroll
        for (int j = 0; j < 8; j++) Bs[(bcb * 8 + j) * 40 + bkr] = p8[j];
    };

    f32x4 acc[4][2] = {};

    const int nk = (kend - kbeg) >> 5;
    loadT(kbeg);
    for (int t = 0; t < nk; ++t) {
        storeT();
        __syncthreads();
        if (t + 1 < nk) loadT(kbeg + ((t + 1) << 5));
        bf16x8 af[4], bfr[2];
#pragma unroll
        for (int fm = 0; fm < 4; fm++)
            af[fm] = *(const bf16x8*)(&As[(wr * 64 + fm * 16 + lr) * 40 + g * 8]);
#pragma unroll
        for (int fn = 0; fn < 2; fn++)
            bfr[fn] = *(const bf16x8*)(&Bs[(wc * 32 + fn * 16 + lr) * 40 + g * 8]);
#pragma unroll
        for (int fm = 0; fm < 4; fm++)
#pragma unroll
            for (int fn = 0; fn < 2; fn++)
                acc[fm][fn] = __builtin_amdgcn_mfma_f32_16x16x32_bf16(af[fm], bfr[fn], acc[fm][fn], 0, 0, 0);
        __syncthreads();
    }

    if (SPLIT) {
        float* P = Cf + (long)blockIdx.z * M * N;
#pragma unroll
        for (int fm = 0; fm < 4; fm++)
#pragma unroll
            for (int fn = 0; fn < 2; fn++)
#pragma unroll
                for (int rr = 0; rr < 4; rr++) {
                    long row = m0 + wr * 64 + fm * 16 + g * 4 + rr;
                    int  col = n0 + wc * 32 + fn * 16 + lr;
                    P[row * N + col] = acc[fm][fn][rr];
                }
    } else {
#pragma unroll
        for (int fm = 0; fm < 4; fm++)
#pragma unroll
            for (int fn = 0; fn < 2; fn++)
#pragma unroll
                for (int rr = 0; rr < 4; rr++) {
                    long row = m0 + wr * 64 + fm * 16 + g * 4 + rr;
                    int  col = n0 + wc * 32 + fn * 16 + lr;
                    float v = acc[fm][fn][rr];
                    if (HAS_BIAS) v += bias[col];
                    if (RELU) v = fmaxf(v, 0.f);
                    if (BF16_OUT) Cb[row * ldc + col] = f2bf(v);
                    else          Cf[row * ldc + col] = v;
                }
    }
}

// sum nz split-K partials -> bf16
__global__ __launch_bounds__(256) void reduce_add_bf16(const float* __restrict__ P,
                                                       ushort* __restrict__ C, int MN, int nz)
{
    int i = blockIdx.x * 256 + threadIdx.x;
    int n4 = MN >> 2;
    if (i >= n4) return;
    f32x4 a = ((const f32x4*)P)[i];
    for (int z = 1; z < nz; z++) a += ((const f32x4*)(P + (long)z * MN))[i];
    ushort4 o; o.x = f2bf(a.x); o.y = f2bf(a.y); o.z = f2bf(a.z); o.w = f2bf(a.w);
    ((ushort4*)C)[i] = o;
}

// prep: A->bf16, X_n->bf16, 3 weight transposes, zero stats. One launch.
__global__ __launch_bounds__(256) void prep_k(const float* __restrict__ A, ushort* __restrict__ Abf,
                                              const float* __restrict__ Xn, ushort* __restrict__ Xnb,
                                              const float* __restrict__ W1, ushort* __restrict__ W1t,
                                              const float* __restrict__ W2, ushort* __restrict__ W2t,
                                              const float* __restrict__ Wh, ushort* __restrict__ Wht,
                                              float* __restrict__ stats)
{
    int b = blockIdx.x, t = threadIdx.x;
    if (b < 8192) {                       // A: 16.78M elems, 8/thread
        long j = (long)b * 256 + t;
        f32x4 v0 = ((const f32x4*)A)[2 * j];
        f32x4 v1 = ((const f32x4*)A)[2 * j + 1];
        u32x4 w;
        w.x = pk2(v0.x, v0.y); w.y = pk2(v0.z, v0.w);
        w.z = pk2(v1.x, v1.y); w.w = pk2(v1.z, v1.w);
        ((u32x4*)Abf)[j] = w;
    } else if (b < 8448) {                // X_n
        long j = (long)(b - 8192) * 256 + t;
        f32x4 v0 = ((const f32x4*)Xn)[2 * j];
        f32x4 v1 = ((const f32x4*)Xn)[2 * j + 1];
        u32x4 w;
        w.x = pk2(v0.x, v0.y); w.y = pk2(v0.z, v0.w);
        w.z = pk2(v1.x, v1.y); w.w = pk2(v1.z, v1.w);
        ((u32x4*)Xnb)[j] = w;
    } else if (b < 8576) {                // W1 [256,128] -> T [128,256]
        int j = (b - 8448) * 256 + t;
        int i = j >> 8, o = j & 255;
        W1t[j] = f2bf(W1[o * 128 + i]);
    } else if (b < 8832) {                // W2 [256,256] -> T [256,256]
        int j = (b - 8576) * 256 + t;
        int i = j >> 8, o = j & 255;
        W2t[j] = f2bf(W2[o * 256 + i]);
    } else if (b < 8848) {                // Wh [64,64] -> T [64,64]
        int j = (b - 8832) * 256 + t;
        int i = j >> 6, o = j & 63;
        Wht[j] = f2bf(Wh[o * 64 + i]);
    } else {
        if (t < 192) stats[t] = 0.f;
    }
}

// fused: Zc1 = sum of 4 partials; column sum/sumsq stats. grid 256 x 256
__global__ __launch_bounds__(256) void bnred_k(const float* __restrict__ P,
                                               float* __restrict__ Zc,
                                               float* __restrict__ gsum, float* __restrict__ gsq)
{
    const int MN = 8192 * 64;
    int b = blockIdx.x, t = threadIdx.x;
    int c = t & 63, rg = t >> 6;
    float sx = 0.f, sq = 0.f;
    int base = b * 32 + rg;
#pragma unroll 4
    for (int i = 0; i < 8; i++) {
        long idx = (long)(base + 4 * i) * 64 + c;
        float x = P[idx] + P[idx + MN] + P[idx + 2 * MN] + P[idx + 3 * MN];
        Zc[idx] = x;
        sx += x; sq += x * x;
    }
    __shared__ float ls[256], lq[256];
    ls[t] = sx; lq[t] = sq;
    __syncthreads();
    if (t < 64) {
        float a = ls[t] + ls[t + 64] + ls[t + 128] + ls[t + 192];
        float q = lq[t] + lq[t + 64] + lq[t + 128] + lq[t + 192];
        atomicAdd(&gsum[t], a);
        atomicAdd(&gsq[t], q);
    }
}

// Z1[row] = max_c relu(bn(Zc1[row,c])); wave per row, grid 2048 x 256
__global__ __launch_bounds__(256) void z1_k(const float* __restrict__ Zc,
                                            const float* __restrict__ gsum, const float* __restrict__ gsq,
                                            const float* __restrict__ g, const float* __restrict__ b,
                                            float* __restrict__ Z1)
{
    int w = threadIdx.x >> 6, lane = threadIdx.x & 63;
    int row = blockIdx.x * 4 + w;
    const float inv = 1.f / 8192.f;
    float m = gsum[lane] * inv;
    float v = gsq[lane] * inv - m * m;
    float x = Zc[row * 64 + lane];
    float y = fmaxf(g[lane] * (x - m) * rsqrtf(v + 1e-5f) + b[lane], 0.f);
#pragma unroll
    for (int o = 32; o > 0; o >>= 1) y = fmaxf(y, __shfl_xor(y, o));
    if (lane == 0) Z1[row] = y;
}

// s[i]=L1[i,:].Z1 ; r[i]=rowsum(L1[i,:]); block per row, grid 8192 x 256
__global__ __launch_bounds__(256) void pass2_k(const float* __restrict__ L1, const float* __restrict__ Z1,
                                               float* __restrict__ s, float* __restrict__ r)
{
    int row = blockIdx.x, t = threadIdx.x;
    int l = t & 63, w = t >> 6;
    const f32x4* rp = (const f32x4*)(L1 + (long)row * 8192);
    const f32x4* z4 = (const f32x4*)Z1;
    float as = 0.f, ar = 0.f;
#pragma unroll 4
    for (int k = 0; k < 8; k++) {
        f32x4 v = rp[t + 256 * k];
        f32x4 z = z4[t + 256 * k];
        as += v.x * z.x + v.y * z.y + v.z * z.z + v.w * z.w;
        ar += v.x + v.y + v.z + v.w;
    }
#pragma unroll
    for (int o = 32; o > 0; o >>= 1) { as += __shfl_xor(as, o); ar += __shfl_xor(ar, o); }
    __shared__ float sw[4], rw[4];
    if (l == 0) { sw[w] = as; rw[w] = ar; }
    __syncthreads();
    if (t == 0) {
        s[row] = sw[0] + sw[1] + sw[2] + sw[3];
        r[row] = rw[0] + rw[1] + rw[2] + rw[3];
    }
}

// single block: 5 moments of (s, r) over 8192 rows
__global__ __launch_bounds__(256) void stats2_k(const float* __restrict__ s, const float* __restrict__ r,
                                                float* __restrict__ S5)
{
    int t = threadIdx.x, l = t & 63, w = t >> 6;
    float Ss = 0, Sr = 0, Sss = 0, Srr = 0, Ssr = 0;
    for (int i = t; i < 8192; i += 256) {
        float sv = s[i], rv = r[i];
        Ss += sv; Sr += rv; Sss += sv * sv; Srr += rv * rv; Ssr += sv * rv;
    }
#pragma unroll
    for (int o = 32; o > 0; o >>= 1) {
        Ss += __shfl_xor(Ss, o); Sr += __shfl_xor(Sr, o);
        Sss += __shfl_xor(Sss, o); Srr += __shfl_xor(Srr, o); Ssr += __shfl_xor(Ssr, o);
    }
    __shared__ float buf[4][5];
    if (l == 0) { buf[w][0] = Ss; buf[w][1] = Sr; buf[w][2] = Sss; buf[w][3] = Srr; buf[w][4] = Ssr; }
    __syncthreads();
    if (t < 5) S5[t] = buf[0][t] + buf[1][t] + buf[2][t] + buf[3][t];
}

// Z2 + edge_prob; wave per row; grid 2048 x 256
__global__ __launch_bounds__(256) void z2_edge_k(const float* __restrict__ s, const float* __restrict__ r,
                                                 const float* __restrict__ S,
                                                 const float* __restrict__ W2, const float* __restrict__ b2,
                                                 const float* __restrict__ g2, const float* __restrict__ bb2,
                                                 const float* __restrict__ eW, const float* __restrict__ eb,
                                                 const float* __restrict__ Z1,
                                                 float* __restrict__ Z2, float* __restrict__ edge_out)
{
    int w = threadIdx.x >> 6, lane = threadIdx.x & 63;
    int row = blockIdx.x * 4 + w;
    const float inv = 1.f / 8192.f;
    float ms = S[0] * inv, mr = S[1] * inv;
    float vs = S[2] * inv - ms * ms;
    float vr = S[3] * inv - mr * mr;
    float cv = S[4] * inv - ms * mr;
    float w2 = W2[lane], bz = b2[lane];
    float mc = w2 * ms + bz * mr;
    float vc = w2 * w2 * vs + 2.f * w2 * bz * cv + bz * bz * vr;
    float x  = w2 * s[row] + bz * r[row];
    float y  = fmaxf(g2[lane] * (x - mc) * rsqrtf(vc + 1e-5f) + bb2[lane], 0.f);
#pragma unroll
    for (int o = 32; o > 0; o >>= 1) y = fmaxf(y, __shfl_xor(y, o));
    if (lane == 0) {
        Z2[row] = y;
        float e = Z1[row] * eW[0] + y * eW[1] + eb[0];
        edge_out[row] = sigmoidf_(e);
    }
}

// H_e (B1@[Z1 Z2]) into hcat cols 256/257 + node head; block per row, grid 4096
__global__ __launch_bounds__(256) void he_node_k(const float* __restrict__ B1, const float* __restrict__ Z1,
                                                 const float* __restrict__ Z2, float* __restrict__ hcat,
                                                 const float* __restrict__ nW, const float* __restrict__ nb,
                                                 float* __restrict__ node_out)
{
    int n = blockIdx.x, t = threadIdx.x;
    int l = t & 63, w = t >> 6;
    const f32x4* rp  = (const f32x4*)(B1 + (long)n * 8192);
    const f32x4* z1v = (const f32x4*)Z1;
    const f32x4* z2v = (const f32x4*)Z2;
    float a1 = 0.f, a2 = 0.f;
#pragma unroll 4
    for (int k = 0; k < 8; k++) {
        f32x4 v = rp[t + 256 * k];
        f32x4 p = z1v[t + 256 * k];
        f32x4 q = z2v[t + 256 * k];
        a1 += v.x * p.x + v.y * p.y + v.z * p.z + v.w * p.w;
        a2 += v.x * q.x + v.y * q.y + v.z * q.z + v.w * q.w;
    }
    float d = hcat[(long)n * 258 + t] * nW[t];
#pragma unroll
    for (int o = 32; o > 0; o >>= 1) {
        a1 += __shfl_xor(a1, o); a2 += __shfl_xor(a2, o); d += __shfl_xor(d, o);
    }
    __shared__ float s1[4], s2[4], s3[4];
    if (l == 0) { s1[w] = a1; s2[w] = a2; s3[w] = d; }
    __syncthreads();
    if (t == 0) {
        float A1 = s1[0] + s1[1] + s1[2] + s1[3];
        float A2 = s2[0] + s2[1] + s2[2] + s2[3];
        float D  = s3[0] + s3[1] + s3[2] + s3[3];
        hcat[(long)n * 258 + 256] = A1;
        hcat[(long)n * 258 + 257] = A2;
        node_out[n] = sigmoidf_(D + A1 * nW[256] + A2 * nW[257] + nb[0]);
    }
}

// hyperedge gather-mean-dot-sigmoid; wave per hyperedge; grid 256 x 256
__global__ __launch_bounds__(256) void hyper_k(const void* __restrict__ he_idx,
                                               const float* __restrict__ hcat,
                                               const float* __restrict__ hW, const float* __restrict__ hb,
                                               float* __restrict__ out)
{
    int w = threadIdx.x >> 6, lane = threadIdx.x & 63;
    int h = blockIdx.x * 4 + w;
    const unsigned int* u = (const unsigned int*)he_idx;
    unsigned int odd = u[2 * lane + 1];
    bool is64 = __all(odd == 0u);
    float acc = 0.f;
    for (int k = 0; k < 8; k++) {
        int idx;
        if (is64) idx = (int)((const long long*)he_idx)[h * 8 + k];
        else      idx = ((const int*)he_idx)[h * 8 + k];
        const float* hr = hcat + (long)idx * 258;
        for (int d = lane; d < 258; d += 64) acc += hr[d] * hW[d];
    }
    acc *= 0.125f;
#pragma unroll
    for (int o = 32; o > 0; o >>= 1) acc += __shfl_xor(acc, o);
    if (lane == 0) out[h] = sigmoidf_(acc + hb[0]);
}

// ---------------------------------------------------------------------------
extern "C" void kernel_launch(void* const* d_in, const int* in_sizes, int n_in,
                              void* d_out, int out_size, void* d_ws, size_t ws_size,
                              hipStream_t stream)
{
    const float* X_n  = (const float*)d_in[0];
    const float* X_e  = (const float*)d_in[1];
    const float* A_t  = (const float*)d_in[2];
    const float* L1   = (const float*)d_in[3];
    const float* B1   = (const float*)d_in[4];
    const float* gW1  = (const float*)d_in[5];
    const float* gb1  = (const float*)d_in[6];
    const float* gW2  = (const float*)d_in[7];
    const float* gb2  = (const float*)d_in[8];
    const float* hW1  = (const float*)d_in[9];
    const float* hb1  = (const float*)d_in[10];
    const float* bn1g = (const float*)d_in[11];
    const float* bn1b = (const float*)d_in[12];
    const float* hW2  = (const float*)d_in[13];
    const float* hb2  = (const float*)d_in[14];
    const float* bn2g = (const float*)d_in[15];
    const float* bn2b = (const float*)d_in[16];
    const float* nW   = (const float*)d_in[17];
    const float* nb   = (const float*)d_in[18];
    const float* eW   = (const float*)d_in[19];
    const float* ebb  = (const float*)d_in[20];
    const float* yW   = (const float*)d_in[21];
    const float* yb   = (const float*)d_in[22];
    const void*  he   = d_in[23];

    float* out       = (float*)d_out;
    float* out_node  = out;              // 4096
    float* out_edge  = out + 4096;       // 8192
    float* out_hyper = out + 12288;      // 1024
    float* hcat      = out + 13312;      // 4096 x 258

    size_t off = 0;
    auto alloc = [&](size_t bytes) {
        void* p = (char*)d_ws + off;
        off = (off + bytes + 255) & ~(size_t)255;
        return p;
    };
    ushort* Abf   = (ushort*)alloc((size_t)4096 * 4096 * 2);  // 33.5 MB
    ushort* Xn_bf = (ushort*)alloc(4096 * 128 * 2);
    ushort* W1t   = (ushort*)alloc(128 * 256 * 2);
    ushort* W2t   = (ushort*)alloc(256 * 256 * 2);
    ushort* W1ht  = (ushort*)alloc(64 * 64 * 2);
    ushort* C1b   = (ushort*)alloc(4096 * 128 * 2);
    ushort* H_bf  = (ushort*)alloc(4096 * 256 * 2);
    ushort* C2b   = (ushort*)alloc(4096 * 256 * 2);
    ushort* Zt1   = (ushort*)alloc(8192 * 64 * 2);
    float*  Zc1   = (float*)alloc(8192 * 64 * 4);
    float*  stats = (float*)alloc(256 * 4);   // gsum[64], gsq[64], S5[5]
    float*  gsum  = stats;
    float*  gsq   = stats + 64;
    float*  S5    = stats + 128;
    float*  Z1    = (float*)alloc(8192 * 4);
    float*  Z2    = (float*)alloc(8192 * 4);
    float*  sbuf  = (float*)alloc(8192 * 4);
    float*  rbuf  = (float*)alloc(8192 * 4);
    float*  P     = (float*)alloc((size_t)2097152 * 4);  // split-K partials (8 MB)

    // prep: converts + transposes + stat zero (1 launch)
    prep_k<<<8849, 256, 0, stream>>>(A_t, Abf, X_n, Xn_bf, gW1, W1t, gW2, W2t, hW1, W1ht, stats);

    // GNN
    gemm_kernel<true, true, false, false, false><<<dim3(32, 2, 4), 256, 0, stream>>>(
        Abf, Xn_bf, nullptr, P, nullptr, 4096, 128, 4096, 128, 1024);
    reduce_add_bf16<<<512, 256, 0, stream>>>(P, C1b, 4096 * 128, 4);
    gemm_kernel<true, false, true, true, true><<<dim3(32, 4, 1), 256, 0, stream>>>(
        C1b, W1t, gb1, nullptr, H_bf, 4096, 256, 128, 256, 0);
    gemm_kernel<true, true, false, false, false><<<dim3(32, 4, 2), 256, 0, stream>>>(
        Abf, H_bf, nullptr, P, nullptr, 4096, 256, 4096, 256, 2048);
    reduce_add_bf16<<<1024, 256, 0, stream>>>(P, C2b, 4096 * 256, 2);
    gemm_kernel<true, false, true, false, true><<<dim3(32, 4, 1), 256, 0, stream>>>(
        C2b, W2t, gb2, hcat, nullptr, 4096, 256, 256, 258, 0);

    // HoSC layer 1
    gemm_kernel<false, false, false, true, true><<<dim3(64, 1, 1), 256, 0, stream>>>(
        X_e, W1ht, hb1, nullptr, Zt1, 8192, 64, 64, 64, 0);
    gemm_kernel<false, true, false, false, false><<<dim3(64, 1, 4), 256, 0, stream>>>(
        L1, Zt1, nullptr, P, nullptr, 8192, 64, 8192, 64, 2048);
    bnred_k<<<256, 256, 0, stream>>>(P, Zc1, gsum, gsq);
    z1_k<<<2048, 256, 0, stream>>>(Zc1, gsum, gsq, bn1g, bn1b, Z1);

    // HoSC layer 2 (rank-1 collapse)
    pass2_k<<<8192, 256, 0, stream>>>(L1, Z1, sbuf, rbuf);
    stats2_k<<<1, 256, 0, stream>>>(sbuf, rbuf, S5);
    z2_edge_k<<<2048, 256, 0, stream>>>(sbuf, rbuf, S5, hW2, hb2, bn2g, bn2b,
                                        eW, ebb, Z1, Z2, out_edge);

    // fuse + heads
    he_node_k<<<4096, 256, 0, stream>>>(B1, Z1, Z2, hcat, nW, nb, out_node);
    hyper_k<<<256, 256, 0, stream>>>(he, hcat, yW, yb, out_hyper);
}